// Round 10
// baseline (523.935 us; speedup 1.0000x reference)
//
#include <hip/hip_runtime.h>
#include <climits>

#define D 128
#define TR 32            // tile rows
#define TS 132           // padded LDS row stride (floats): +4 banks per row

typedef float f32x4 __attribute__((ext_vector_type(4)));
typedef float f32x2 __attribute__((ext_vector_type(2)));
typedef int   i32x2 __attribute__((ext_vector_type(2)));

// ---- CSR step 1: histogram + per-edge arrival rank (rank call-varying; sort canonicalizes) ----
__global__ __launch_bounds__(256) void hist_rank_kernel(const int* __restrict__ erow,
                                                        int* __restrict__ deg,
                                                        int* __restrict__ rank, int nE) {
    int e = blockIdx.x * 256 + threadIdx.x;
    if (e < nE) rank[e] = atomicAdd(&deg[erow[e]], 1);
}

// ---- scan phase 1: per-block (1024 elems) inclusive scan ----
__global__ __launch_bounds__(256) void scan1_kernel(const int* __restrict__ deg,
                                                    int* __restrict__ rowptr,
                                                    int* __restrict__ blocksums, int n) {
    __shared__ int sd[256];
    const int t = threadIdx.x;
    const int idx = blockIdx.x * 1024 + t * 4;
    int4 v = make_int4(0, 0, 0, 0);
    if (idx + 3 < n) v = *(const int4*)&deg[idx];
    else {
        if (idx + 0 < n) v.x = deg[idx + 0];
        if (idx + 1 < n) v.y = deg[idx + 1];
        if (idx + 2 < n) v.z = deg[idx + 2];
        if (idx + 3 < n) v.w = deg[idx + 3];
    }
    const int s = v.x + v.y + v.z + v.w;
    sd[t] = s;
    __syncthreads();
    for (int off = 1; off < 256; off <<= 1) {
        int tv = (t >= off) ? sd[t - off] : 0;
        __syncthreads();
        sd[t] += tv;
        __syncthreads();
    }
    const int excl = sd[t] - s;
    int a = excl + v.x, b = a + v.y, c = b + v.z, d = c + v.w;
    if (idx + 0 < n) rowptr[idx + 1] = a;
    if (idx + 1 < n) rowptr[idx + 2] = b;
    if (idx + 2 < n) rowptr[idx + 3] = c;
    if (idx + 3 < n) rowptr[idx + 4] = d;
    if (t == 255) blocksums[blockIdx.x] = sd[255];
}

// ---- scan phase 2: exclusive scan of block sums (nb <= 256) ----
__global__ __launch_bounds__(256) void scan2_kernel(int* __restrict__ blocksums, int nb) {
    __shared__ int sd[256];
    const int t = threadIdx.x;
    const int v = (t < nb) ? blocksums[t] : 0;
    sd[t] = v;
    __syncthreads();
    for (int off = 1; off < 256; off <<= 1) {
        int tv = (t >= off) ? sd[t - off] : 0;
        __syncthreads();
        sd[t] += tv;
        __syncthreads();
    }
    if (t < nb) blocksums[t] = sd[t] - v;   // exclusive
}

// ---- scan phase 3: add block offsets; finalize rowptr ----
__global__ __launch_bounds__(256) void scan3_kernel(int* __restrict__ rowptr,
                                                    const int* __restrict__ blocksums, int n) {
    int i = blockIdx.x * 256 + threadIdx.x;
    if (i < n) rowptr[i + 1] += blocksums[i >> 10];
    if (i == 0) rowptr[0] = 0;
}

// ---- CSR placement: one packed 8B record {col, valbits} per edge; no atomics ----
__global__ __launch_bounds__(256) void place_kernel(const int* __restrict__ erow,
                                                    const int* __restrict__ rank,
                                                    const int* __restrict__ ecol,
                                                    const float* __restrict__ ev,
                                                    const int* __restrict__ rowptr,
                                                    i32x2* __restrict__ cv, int nE) {
    int e = blockIdx.x * 256 + threadIdx.x;
    if (e >= nE) return;
    int pos = rowptr[erow[e]] + rank[e];
    i32x2 rec;
    rec.x = ecol[e];
    rec.y = __float_as_int(ev[e]);
    cv[pos] = rec;
}

// ---- canonicalize: wave rank-sort each row's records by u64(col,valbits) ----
__global__ __launch_bounds__(256) void sortrow_wave_kernel(const int* __restrict__ rowptr,
                                                           i32x2* __restrict__ cv, int n) {
    int row = blockIdx.x * 4 + (threadIdx.x >> 6);
    if (row >= n) return;
    const int lane = threadIdx.x & 63;
    const int s = rowptr[row], e = rowptr[row + 1];
    const int deg = e - s;
    if (deg <= 1) return;
    if (deg <= 64) {
        unsigned long long key = ~0ull;
        i32x2 rec;
        rec.x = 0; rec.y = 0;
        if (lane < deg) {
            rec = cv[s + lane];
            key = ((unsigned long long)(unsigned)rec.x << 32) | (unsigned)rec.y;
        }
        int rank = 0;
        for (int i = 0; i < deg; ++i) {
            unsigned long long ki = __shfl(key, i);
            rank += (ki < key || (ki == key && i < lane)) ? 1 : 0;
        }
        if (lane < deg) cv[s + rank] = rec;   // wave-lockstep: reads precede writes
    } else if (lane == 0) {                   // deg>64: ~never (deg ~ Poisson(16))
        for (int i = s + 1; i < e; ++i) {
            i32x2 r_ = cv[i];
            unsigned long long k_ = ((unsigned long long)(unsigned)r_.x << 32) | (unsigned)r_.y;
            int j = i - 1;
            while (j >= s) {
                i32x2 rj = cv[j];
                unsigned long long kj = ((unsigned long long)(unsigned)rj.x << 32) | (unsigned)rj.y;
                if (kj <= k_) break;
                cv[j + 1] = rj;
                --j;
            }
            cv[j + 1] = r_;
        }
    }
}

// ---- fused layer: [gather 32-row tile into LDS] -> [tile @ W, relu] -> h or classify ----
template <bool CLASSIFY>
__global__ __launch_bounds__(256, 4) void fused_layer_kernel(
        const float* __restrict__ h, const int* __restrict__ rowptr,
        const i32x2* __restrict__ cv, const float* __restrict__ W,
        const float* __restrict__ Cls, float* __restrict__ O, int n) {
    __shared__ float tile[TR * TS];                      // 16.5 KB, padded stride
    __shared__ float cls_s[CLASSIFY ? D * 16 : 1];       // 8 KB when classifying

    if (CLASSIFY) {
        for (int i = threadIdx.x * 8; i < D * 16; i += 256 * 8) {
            *(f32x4*)&cls_s[i]     = *(const f32x4*)&Cls[i];
            *(f32x4*)&cls_s[i + 4] = *(const f32x4*)&Cls[i + 4];
        }
    }

    const int row0 = blockIdx.x * TR;

    // ---- phase 1: gather (pull SpMM) into LDS tile; 8 rows in parallel, 4 iters ----
    {
        const int rp = threadIdx.x >> 5;          // row slot 0..7
        const int l = threadIdx.x & 31;
        const f32x4* hl = (const f32x4*)h + l;
        for (int i = 0; i < 4; ++i) {
            const int rl = i * 8 + rp;            // local row 0..31
            const int r = row0 + rl;
            f32x4 acc = (f32x4)(0.f);
            if (r < n) {
                const int s = rowptr[r], e = rowptr[r + 1];
                int k = s;
                for (; k + 8 <= e; k += 8) {
                    i32x2 p[8];
#pragma unroll
                    for (int u = 0; u < 8; ++u) p[u] = cv[k + u];
                    f32x4 hv[8];
#pragma unroll
                    for (int u = 0; u < 8; ++u) hv[u] = hl[(size_t)p[u].x * 32];
#pragma unroll
                    for (int u = 0; u < 8; ++u) acc += __int_as_float(p[u].y) * hv[u];
                }
                for (; k < e; ++k) {
                    i32x2 p = cv[k];
                    acc += __int_as_float(p.y) * hl[(size_t)p.x * 32];
                }
            }
            *(f32x4*)&tile[rl * TS + l * 4] = acc;
        }
    }
    __syncthreads();

    // ---- phase 2: tile(32x128) @ W(128x128), relu; 2 rows x 8 cols per thread ----
    const int cg = threadIdx.x & 15;    // 16 col groups of 8
    const int rq = threadIdx.x >> 4;    // 16 row pairs
    const int c0 = cg * 8;

    float acc[2][8];
#pragma unroll
    for (int r = 0; r < 2; ++r)
#pragma unroll
        for (int c = 0; c < 8; ++c) acc[r][c] = 0.f;

    for (int k = 0; k < D; k += 4) {
        f32x4 a[2];
#pragma unroll
        for (int r = 0; r < 2; ++r) a[r] = *(const f32x4*)&tile[(rq * 2 + r) * TS + k];
#pragma unroll
        for (int kk = 0; kk < 4; ++kk) {
            const float* wrow = &W[(k + kk) * D + c0];
            f32x4 w0 = *(const f32x4*)&wrow[0];
            f32x4 w1 = *(const f32x4*)&wrow[4];
#pragma unroll
            for (int r = 0; r < 2; ++r) {
                float av = a[r][kk];
                acc[r][0] += av * w0.x; acc[r][1] += av * w0.y;
                acc[r][2] += av * w0.z; acc[r][3] += av * w0.w;
                acc[r][4] += av * w1.x; acc[r][5] += av * w1.y;
                acc[r][6] += av * w1.z; acc[r][7] += av * w1.w;
            }
        }
    }

    if (!CLASSIFY) {
        // write h rows
#pragma unroll
        for (int r = 0; r < 2; ++r) {
            int row = row0 + rq * 2 + r;
            if (row >= n) continue;
            f32x4 v0, v1;
            v0.x = fmaxf(acc[r][0], 0.f); v0.y = fmaxf(acc[r][1], 0.f);
            v0.z = fmaxf(acc[r][2], 0.f); v0.w = fmaxf(acc[r][3], 0.f);
            v1.x = fmaxf(acc[r][4], 0.f); v1.y = fmaxf(acc[r][5], 0.f);
            v1.z = fmaxf(acc[r][6], 0.f); v1.w = fmaxf(acc[r][7], 0.f);
            *(f32x4*)&O[(size_t)row * D + c0]     = v0;
            *(f32x4*)&O[(size_t)row * D + c0 + 4] = v1;
        }
    } else {
        // overwrite tile with relu(h), then classify from LDS
        __syncthreads();
#pragma unroll
        for (int r = 0; r < 2; ++r) {
            f32x4 v0, v1;
            v0.x = fmaxf(acc[r][0], 0.f); v0.y = fmaxf(acc[r][1], 0.f);
            v0.z = fmaxf(acc[r][2], 0.f); v0.w = fmaxf(acc[r][3], 0.f);
            v1.x = fmaxf(acc[r][4], 0.f); v1.y = fmaxf(acc[r][5], 0.f);
            v1.z = fmaxf(acc[r][6], 0.f); v1.w = fmaxf(acc[r][7], 0.f);
            *(f32x4*)&tile[(rq * 2 + r) * TS + c0]     = v0;
            *(f32x4*)&tile[(rq * 2 + r) * TS + c0 + 4] = v1;
        }
        __syncthreads();
        // phase 3: 32 rows x 16 classes; 2 logits per thread
        const int rl = threadIdx.x >> 3;       // 0..31
        const int q = threadIdx.x & 7;         // class pair index
        float lg0 = 0.f, lg1 = 0.f;
        for (int k = 0; k < D; ++k) {
            float hv = tile[rl * TS + k];
            lg0 += hv * cls_s[k * 16 + q * 2];
            lg1 += hv * cls_s[k * 16 + q * 2 + 1];
        }
        int row = row0 + rl;
        if (row < n) {
            f32x2 o;
            o.x = lg0 > 0.f ? 1.f : 0.f;
            o.y = lg1 > 0.f ? 1.f : 0.f;
            *(f32x2*)&O[(size_t)row * 16 + q * 2] = o;
        }
    }
}

extern "C" void kernel_launch(void* const* d_in, const int* in_sizes, int n_in,
                              void* d_out, int out_size, void* d_ws, size_t ws_size,
                              hipStream_t stream) {
    const float* x    = (const float*)d_in[0];
    const int*   erow = (const int*)d_in[1];
    const int*   ecol = (const int*)d_in[2];
    const float* ev   = (const float*)d_in[3];
    const float* w1   = (const float*)d_in[4];
    const float* w2   = (const float*)d_in[5];
    const float* cls  = (const float*)d_in[6];

    const int n  = in_sizes[0] / D;   // 100000
    const int nE = in_sizes[1];       // 1600000

    // workspace layout
    char*  ws     = (char*)d_ws;
    float* h      = (float*)ws;                 ws += (size_t)n * D * 4;   // 51.2 MB
    int*   deg    = (int*)ws;                   ws += (size_t)n * 4;
    int*   rowptr = (int*)ws;                   ws += (size_t)(n + 1) * 4;
    int*   rank   = (int*)ws;                   ws += (size_t)nE * 4;
    i32x2* cv     = (i32x2*)ws;                 ws += (size_t)nE * 8;      // packed col+val
    int*   bsums  = (int*)ws;                   ws += 256 * 4;

    const int nb = (n + 1023) / 1024;   // 98 <= 256

    dim3 blk(256);
    dim3 egrid((nE + 255) / 256);
    dim3 ngrid((n + 255) / 256);
    dim3 wgrid((n + 3) / 4);          // sortrow: 1 wave per row
    dim3 fgrid((n + TR - 1) / TR);    // fused layers: 32 rows per block

    // ---- CSR build (deterministic final order by (col,valbits)) ----
    (void)hipMemsetAsync(deg, 0, (size_t)n * 4, stream);
    hist_rank_kernel<<<egrid, blk, 0, stream>>>(erow, deg, rank, nE);
    scan1_kernel<<<nb, blk, 0, stream>>>(deg, rowptr, bsums, n);
    scan2_kernel<<<1, blk, 0, stream>>>(bsums, nb);
    scan3_kernel<<<ngrid, blk, 0, stream>>>(rowptr, bsums, n);
    place_kernel<<<egrid, blk, 0, stream>>>(erow, rank, ecol, ev, rowptr, cv, nE);
    sortrow_wave_kernel<<<wgrid, blk, 0, stream>>>(rowptr, cv, n);

    // ---- layer 1: h = relu(spmm(x) @ w1) ----
    fused_layer_kernel<false><<<fgrid, blk, 0, stream>>>(x, rowptr, cv, w1, nullptr, h, n);

    // ---- layer 2 + classifier: out = (relu(spmm(h) @ w2) @ cls > 0) ----
    fused_layer_kernel<true><<<fgrid, blk, 0, stream>>>(h, rowptr, cv, w2, cls,
                                                        (float*)d_out, n);
}

// Round 11
// 496.434 us; speedup vs baseline: 1.0554x; 1.0554x over previous
//
#include <hip/hip_runtime.h>
#include <climits>

#define D 128
#define TR 64            // tile rows (R9 structure)
#define TS 132           // padded LDS row stride (floats): breaks bank-0 alignment

typedef float f32x4 __attribute__((ext_vector_type(4)));
typedef int   i32x2 __attribute__((ext_vector_type(2)));

// ---- CSR step 1: histogram + per-edge arrival rank (rank call-varying; sort canonicalizes) ----
__global__ __launch_bounds__(256) void hist_rank_kernel(const int* __restrict__ erow,
                                                        int* __restrict__ deg,
                                                        int* __restrict__ rank, int nE) {
    int e = blockIdx.x * 256 + threadIdx.x;
    if (e < nE) rank[e] = atomicAdd(&deg[erow[e]], 1);
}

// ---- scan phase 1: per-block (1024 elems) inclusive scan ----
__global__ __launch_bounds__(256) void scan1_kernel(const int* __restrict__ deg,
                                                    int* __restrict__ rowptr,
                                                    int* __restrict__ blocksums, int n) {
    __shared__ int sd[256];
    const int t = threadIdx.x;
    const int idx = blockIdx.x * 1024 + t * 4;
    int4 v = make_int4(0, 0, 0, 0);
    if (idx + 3 < n) v = *(const int4*)&deg[idx];
    else {
        if (idx + 0 < n) v.x = deg[idx + 0];
        if (idx + 1 < n) v.y = deg[idx + 1];
        if (idx + 2 < n) v.z = deg[idx + 2];
        if (idx + 3 < n) v.w = deg[idx + 3];
    }
    const int s = v.x + v.y + v.z + v.w;
    sd[t] = s;
    __syncthreads();
    for (int off = 1; off < 256; off <<= 1) {
        int tv = (t >= off) ? sd[t - off] : 0;
        __syncthreads();
        sd[t] += tv;
        __syncthreads();
    }
    const int excl = sd[t] - s;
    int a = excl + v.x, b = a + v.y, c = b + v.z, d = c + v.w;
    if (idx + 0 < n) rowptr[idx + 1] = a;
    if (idx + 1 < n) rowptr[idx + 2] = b;
    if (idx + 2 < n) rowptr[idx + 3] = c;
    if (idx + 3 < n) rowptr[idx + 4] = d;
    if (t == 255) blocksums[blockIdx.x] = sd[255];
}

// ---- scan phase 2: exclusive scan of block sums (nb <= 256) ----
__global__ __launch_bounds__(256) void scan2_kernel(int* __restrict__ blocksums, int nb) {
    __shared__ int sd[256];
    const int t = threadIdx.x;
    const int v = (t < nb) ? blocksums[t] : 0;
    sd[t] = v;
    __syncthreads();
    for (int off = 1; off < 256; off <<= 1) {
        int tv = (t >= off) ? sd[t - off] : 0;
        __syncthreads();
        sd[t] += tv;
        __syncthreads();
    }
    if (t < nb) blocksums[t] = sd[t] - v;   // exclusive
}

// ---- scan phase 3: add block offsets; finalize rowptr ----
__global__ __launch_bounds__(256) void scan3_kernel(int* __restrict__ rowptr,
                                                    const int* __restrict__ blocksums, int n) {
    int i = blockIdx.x * 256 + threadIdx.x;
    if (i < n) rowptr[i + 1] += blocksums[i >> 10];
    if (i == 0) rowptr[0] = 0;
}

// ---- CSR placement: one packed 8B record {col, valbits} per edge; no atomics ----
__global__ __launch_bounds__(256) void place_kernel(const int* __restrict__ erow,
                                                    const int* __restrict__ rank,
                                                    const int* __restrict__ ecol,
                                                    const float* __restrict__ ev,
                                                    const int* __restrict__ rowptr,
                                                    i32x2* __restrict__ cv, int nE) {
    int e = blockIdx.x * 256 + threadIdx.x;
    if (e >= nE) return;
    int pos = rowptr[erow[e]] + rank[e];
    i32x2 rec;
    rec.x = ecol[e];
    rec.y = __float_as_int(ev[e]);
    cv[pos] = rec;
}

// ---- canonicalize: wave rank-sort each row's records by u64(col,valbits) ----
__global__ __launch_bounds__(256) void sortrow_wave_kernel(const int* __restrict__ rowptr,
                                                           i32x2* __restrict__ cv, int n) {
    int row = blockIdx.x * 4 + (threadIdx.x >> 6);
    if (row >= n) return;
    const int lane = threadIdx.x & 63;
    const int s = rowptr[row], e = rowptr[row + 1];
    const int deg = e - s;
    if (deg <= 1) return;
    if (deg <= 64) {
        unsigned long long key = ~0ull;
        i32x2 rec;
        rec.x = 0; rec.y = 0;
        if (lane < deg) {
            rec = cv[s + lane];
            key = ((unsigned long long)(unsigned)rec.x << 32) | (unsigned)rec.y;
        }
        int rank = 0;
        for (int i = 0; i < deg; ++i) {
            unsigned long long ki = __shfl(key, i);
            rank += (ki < key || (ki == key && i < lane)) ? 1 : 0;
        }
        if (lane < deg) cv[s + rank] = rec;   // wave-lockstep: reads precede writes
    } else if (lane == 0) {                   // deg>64: ~never (deg ~ Poisson(16))
        for (int i = s + 1; i < e; ++i) {
            i32x2 r_ = cv[i];
            unsigned long long k_ = ((unsigned long long)(unsigned)r_.x << 32) | (unsigned)r_.y;
            int j = i - 1;
            while (j >= s) {
                i32x2 rj = cv[j];
                unsigned long long kj = ((unsigned long long)(unsigned)rj.x << 32) | (unsigned)rj.y;
                if (kj <= k_) break;
                cv[j + 1] = rj;
                --j;
            }
            cv[j + 1] = r_;
        }
    }
}

// ---- fused layer: [gather 64-row tile into LDS] -> [tile @ W, relu] -> h or classify ----
template <bool CLASSIFY>
__global__ __launch_bounds__(256, 4) void fused_layer_kernel(
        const float* __restrict__ h, const int* __restrict__ rowptr,
        const i32x2* __restrict__ cv, const float* __restrict__ W,
        const float* __restrict__ Cls, float* __restrict__ O, int n) {
    __shared__ float tile[TR * TS];                      // 33.8 KB, padded stride

    const int row0 = blockIdx.x * TR;

    // ---- phase 1: gather (pull SpMM) into LDS tile; 2 rows per wave in flight ----
    {
        const int wv = threadIdx.x >> 6;          // wave 0..3
        const int half = (threadIdx.x >> 5) & 1;
        const int l = threadIdx.x & 31;
        const f32x4* hl = (const f32x4*)h + l;
        for (int i = 0; i < 8; ++i) {
            const int rl = wv * 16 + i * 2 + half;   // local row 0..63
            const int r = row0 + rl;
            f32x4 acc = (f32x4)(0.f);
            if (r < n) {
                const int s = rowptr[r], e = rowptr[r + 1];
                int k = s;
                for (; k + 8 <= e; k += 8) {
                    i32x2 p[8];
#pragma unroll
                    for (int u = 0; u < 8; ++u) p[u] = cv[k + u];
                    f32x4 hv[8];
#pragma unroll
                    for (int u = 0; u < 8; ++u) hv[u] = hl[(size_t)p[u].x * 32];
#pragma unroll
                    for (int u = 0; u < 8; ++u) acc += __int_as_float(p[u].y) * hv[u];
                }
                for (; k < e; ++k) {
                    i32x2 p = cv[k];
                    acc += __int_as_float(p.y) * hl[(size_t)p.x * 32];
                }
            }
            *(f32x4*)&tile[rl * TS + l * 4] = acc;
        }
    }
    __syncthreads();

    // ---- phase 2: tile(64x128) @ W(128x128), relu; 4 rows x 8 cols per thread ----
    const int cg = threadIdx.x & 15;    // 16 col groups of 8
    const int rq = threadIdx.x >> 4;    // 16 row quads
    const int c0 = cg * 8;

    float acc[4][8];
#pragma unroll
    for (int r = 0; r < 4; ++r)
#pragma unroll
        for (int c = 0; c < 8; ++c) acc[r][c] = 0.f;

    for (int k = 0; k < D; k += 4) {
        f32x4 a[4];
#pragma unroll
        for (int r = 0; r < 4; ++r) a[r] = *(const f32x4*)&tile[(rq * 4 + r) * TS + k];
#pragma unroll
        for (int kk = 0; kk < 4; ++kk) {
            const float* wrow = &W[(k + kk) * D + c0];
            f32x4 w0 = *(const f32x4*)&wrow[0];
            f32x4 w1 = *(const f32x4*)&wrow[4];
#pragma unroll
            for (int r = 0; r < 4; ++r) {
                float av = a[r][kk];
                acc[r][0] += av * w0.x; acc[r][1] += av * w0.y;
                acc[r][2] += av * w0.z; acc[r][3] += av * w0.w;
                acc[r][4] += av * w1.x; acc[r][5] += av * w1.y;
                acc[r][6] += av * w1.z; acc[r][7] += av * w1.w;
            }
        }
    }

    if (!CLASSIFY) {
        // write h rows
#pragma unroll
        for (int r = 0; r < 4; ++r) {
            int row = row0 + rq * 4 + r;
            if (row >= n) continue;
            f32x4 v0, v1;
            v0.x = fmaxf(acc[r][0], 0.f); v0.y = fmaxf(acc[r][1], 0.f);
            v0.z = fmaxf(acc[r][2], 0.f); v0.w = fmaxf(acc[r][3], 0.f);
            v1.x = fmaxf(acc[r][4], 0.f); v1.y = fmaxf(acc[r][5], 0.f);
            v1.z = fmaxf(acc[r][6], 0.f); v1.w = fmaxf(acc[r][7], 0.f);
            *(f32x4*)&O[(size_t)row * D + c0]     = v0;
            *(f32x4*)&O[(size_t)row * D + c0 + 4] = v1;
        }
    } else {
        // overwrite tile with relu(h), then classify from LDS (Cls via L1; only 8 KB)
        __syncthreads();
#pragma unroll
        for (int r = 0; r < 4; ++r) {
            f32x4 v0, v1;
            v0.x = fmaxf(acc[r][0], 0.f); v0.y = fmaxf(acc[r][1], 0.f);
            v0.z = fmaxf(acc[r][2], 0.f); v0.w = fmaxf(acc[r][3], 0.f);
            v1.x = fmaxf(acc[r][4], 0.f); v1.y = fmaxf(acc[r][5], 0.f);
            v1.z = fmaxf(acc[r][6], 0.f); v1.w = fmaxf(acc[r][7], 0.f);
            *(f32x4*)&tile[(rq * 4 + r) * TS + c0]     = v0;
            *(f32x4*)&tile[(rq * 4 + r) * TS + c0 + 4] = v1;
        }
        __syncthreads();
        // phase 3: 64 rows x 16 classes; 4 logits per thread
        const int rl = threadIdx.x >> 2;       // 0..63
        const int q = threadIdx.x & 3;         // class quad
        f32x4 lg = (f32x4)(0.f);
        for (int k = 0; k < D; ++k) {
            float hv = tile[rl * TS + k];
            f32x4 c = *(const f32x4*)&Cls[k * 16 + q * 4];
            lg += hv * c;
        }
        int row = row0 + rl;
        if (row < n) {
            f32x4 o;
            o.x = lg.x > 0.f ? 1.f : 0.f;
            o.y = lg.y > 0.f ? 1.f : 0.f;
            o.z = lg.z > 0.f ? 1.f : 0.f;
            o.w = lg.w > 0.f ? 1.f : 0.f;
            *(f32x4*)&O[(size_t)row * 16 + q * 4] = o;
        }
    }
}

extern "C" void kernel_launch(void* const* d_in, const int* in_sizes, int n_in,
                              void* d_out, int out_size, void* d_ws, size_t ws_size,
                              hipStream_t stream) {
    const float* x    = (const float*)d_in[0];
    const int*   erow = (const int*)d_in[1];
    const int*   ecol = (const int*)d_in[2];
    const float* ev   = (const float*)d_in[3];
    const float* w1   = (const float*)d_in[4];
    const float* w2   = (const float*)d_in[5];
    const float* cls  = (const float*)d_in[6];

    const int n  = in_sizes[0] / D;   // 100000
    const int nE = in_sizes[1];       // 1600000

    // workspace layout
    char*  ws     = (char*)d_ws;
    float* h      = (float*)ws;                 ws += (size_t)n * D * 4;   // 51.2 MB
    int*   deg    = (int*)ws;                   ws += (size_t)n * 4;
    int*   rowptr = (int*)ws;                   ws += (size_t)(n + 1) * 4;
    int*   rank   = (int*)ws;                   ws += (size_t)nE * 4;
    i32x2* cv     = (i32x2*)ws;                 ws += (size_t)nE * 8;      // packed col+val
    int*   bsums  = (int*)ws;                   ws += 256 * 4;

    const int nb = (n + 1023) / 1024;   // 98 <= 256

    dim3 blk(256);
    dim3 egrid((nE + 255) / 256);
    dim3 ngrid((n + 255) / 256);
    dim3 wgrid((n + 3) / 4);          // sortrow: 1 wave per row
    dim3 fgrid((n + TR - 1) / TR);    // fused layers: 64 rows per block

    // ---- CSR build (deterministic final order by (col,valbits)) ----
    (void)hipMemsetAsync(deg, 0, (size_t)n * 4, stream);
    hist_rank_kernel<<<egrid, blk, 0, stream>>>(erow, deg, rank, nE);
    scan1_kernel<<<nb, blk, 0, stream>>>(deg, rowptr, bsums, n);
    scan2_kernel<<<1, blk, 0, stream>>>(bsums, nb);
    scan3_kernel<<<ngrid, blk, 0, stream>>>(rowptr, bsums, n);
    place_kernel<<<egrid, blk, 0, stream>>>(erow, rank, ecol, ev, rowptr, cv, nE);
    sortrow_wave_kernel<<<wgrid, blk, 0, stream>>>(rowptr, cv, n);

    // ---- layer 1: h = relu(spmm(x) @ w1) ----
    fused_layer_kernel<false><<<fgrid, blk, 0, stream>>>(x, rowptr, cv, w1, nullptr, h, n);

    // ---- layer 2 + classifier: out = (relu(spmm(h) @ w2) @ cls > 0) ----
    fused_layer_kernel<true><<<fgrid, blk, 0, stream>>>(h, rowptr, cv, w2, cls,
                                                        (float*)d_out, n);
}

// Round 12
// 474.394 us; speedup vs baseline: 1.1044x; 1.0465x over previous
//
#include <hip/hip_runtime.h>
#include <climits>

#define D 128

typedef float f32x4 __attribute__((ext_vector_type(4)));
typedef int   i32x2 __attribute__((ext_vector_type(2)));

// ---- CSR step 1: histogram + per-edge arrival rank (rank call-varying; sort canonicalizes) ----
__global__ __launch_bounds__(256) void hist_rank_kernel(const int* __restrict__ erow,
                                                        int* __restrict__ deg,
                                                        int* __restrict__ rank, int nE) {
    int e = blockIdx.x * 256 + threadIdx.x;
    if (e < nE) rank[e] = atomicAdd(&deg[erow[e]], 1);
}

// ---- scan phase 1: per-block (1024 elems) inclusive scan ----
__global__ __launch_bounds__(256) void scan1_kernel(const int* __restrict__ deg,
                                                    int* __restrict__ rowptr,
                                                    int* __restrict__ blocksums, int n) {
    __shared__ int sd[256];
    const int t = threadIdx.x;
    const int idx = blockIdx.x * 1024 + t * 4;
    int4 v = make_int4(0, 0, 0, 0);
    if (idx + 3 < n) v = *(const int4*)&deg[idx];
    else {
        if (idx + 0 < n) v.x = deg[idx + 0];
        if (idx + 1 < n) v.y = deg[idx + 1];
        if (idx + 2 < n) v.z = deg[idx + 2];
        if (idx + 3 < n) v.w = deg[idx + 3];
    }
    const int s = v.x + v.y + v.z + v.w;
    sd[t] = s;
    __syncthreads();
    for (int off = 1; off < 256; off <<= 1) {
        int tv = (t >= off) ? sd[t - off] : 0;
        __syncthreads();
        sd[t] += tv;
        __syncthreads();
    }
    const int excl = sd[t] - s;
    int a = excl + v.x, b = a + v.y, c = b + v.z, d = c + v.w;
    if (idx + 0 < n) rowptr[idx + 1] = a;
    if (idx + 1 < n) rowptr[idx + 2] = b;
    if (idx + 2 < n) rowptr[idx + 3] = c;
    if (idx + 3 < n) rowptr[idx + 4] = d;
    if (t == 255) blocksums[blockIdx.x] = sd[255];
}

// ---- scan phase 2: exclusive scan of block sums (nb <= 256) ----
__global__ __launch_bounds__(256) void scan2_kernel(int* __restrict__ blocksums, int nb) {
    __shared__ int sd[256];
    const int t = threadIdx.x;
    const int v = (t < nb) ? blocksums[t] : 0;
    sd[t] = v;
    __syncthreads();
    for (int off = 1; off < 256; off <<= 1) {
        int tv = (t >= off) ? sd[t - off] : 0;
        __syncthreads();
        sd[t] += tv;
        __syncthreads();
    }
    if (t < nb) blocksums[t] = sd[t] - v;   // exclusive
}

// ---- scan phase 3: add block offsets; finalize rowptr ----
__global__ __launch_bounds__(256) void scan3_kernel(int* __restrict__ rowptr,
                                                    const int* __restrict__ blocksums, int n) {
    int i = blockIdx.x * 256 + threadIdx.x;
    if (i < n) rowptr[i + 1] += blocksums[i >> 10];
    if (i == 0) rowptr[0] = 0;
}

// ---- CSR placement: one packed 8B record {col, valbits} per edge; no atomics ----
__global__ __launch_bounds__(256) void place_kernel(const int* __restrict__ erow,
                                                    const int* __restrict__ rank,
                                                    const int* __restrict__ ecol,
                                                    const float* __restrict__ ev,
                                                    const int* __restrict__ rowptr,
                                                    i32x2* __restrict__ cv, int nE) {
    int e = blockIdx.x * 256 + threadIdx.x;
    if (e >= nE) return;
    int pos = rowptr[erow[e]] + rank[e];
    i32x2 rec;
    rec.x = ecol[e];
    rec.y = __float_as_int(ev[e]);
    cv[pos] = rec;
}

// ---- canonicalize: wave rank-sort each row's records by u64(col,valbits) ----
__global__ __launch_bounds__(256) void sortrow_wave_kernel(const int* __restrict__ rowptr,
                                                           i32x2* __restrict__ cv, int n) {
    int row = blockIdx.x * 4 + (threadIdx.x >> 6);
    if (row >= n) return;
    const int lane = threadIdx.x & 63;
    const int s = rowptr[row], e = rowptr[row + 1];
    const int deg = e - s;
    if (deg <= 1) return;
    if (deg <= 64) {
        unsigned long long key = ~0ull;
        i32x2 rec;
        rec.x = 0; rec.y = 0;
        if (lane < deg) {
            rec = cv[s + lane];
            key = ((unsigned long long)(unsigned)rec.x << 32) | (unsigned)rec.y;
        }
        int rank = 0;
        for (int i = 0; i < deg; ++i) {
            unsigned long long ki = __shfl(key, i);
            rank += (ki < key || (ki == key && i < lane)) ? 1 : 0;
        }
        if (lane < deg) cv[s + rank] = rec;   // wave-lockstep: reads precede writes
    } else if (lane == 0) {                   // deg>64: ~never (deg ~ Poisson(16))
        for (int i = s + 1; i < e; ++i) {
            i32x2 r_ = cv[i];
            unsigned long long k_ = ((unsigned long long)(unsigned)r_.x << 32) | (unsigned)r_.y;
            int j = i - 1;
            while (j >= s) {
                i32x2 rj = cv[j];
                unsigned long long kj = ((unsigned long long)(unsigned)rj.x << 32) | (unsigned)rj.y;
                if (kj <= k_) break;
                cv[j + 1] = rj;
                --j;
            }
            cv[j + 1] = r_;
        }
    }
}

// ---- per-wave fused spmm+GEMM(+classify): no LDS, no barriers ----
// Wave handles 8 rows: gather into registers (lanes 0-31 = even rows, 32-63 = odd),
// then GEMM epilogue via shfl-broadcast of h[k] against coalesced W loads.
template <bool CLASSIFY>
__global__ __launch_bounds__(256) void spmm_gemm_kernel(
        const float* __restrict__ h, const int* __restrict__ rowptr,
        const i32x2* __restrict__ cv, const float* __restrict__ W,
        const float* __restrict__ Cls, float* __restrict__ O, int n) {
    const int wid = (blockIdx.x * 256 + threadIdx.x) >> 6;   // global wave id
    const int lane = threadIdx.x & 63;
    const int half = lane >> 5;          // 0: rows +0,2,4,6 ; 1: rows +1,3,5,7
    const int l = lane & 31;
    const int row0 = wid * 8;
    if (row0 >= n) return;

    // ---- phase 1: gather 4 rows per half into registers ----
    const f32x4* hl = (const f32x4*)h + l;
    f32x4 rowdata[4];
#pragma unroll
    for (int i = 0; i < 4; ++i) {
        const int r = row0 + 2 * i + half;
        f32x4 acc = (f32x4)(0.f);
        if (r < n) {
            const int s = rowptr[r], e = rowptr[r + 1];
            int k = s;
            for (; k + 8 <= e; k += 8) {
                i32x2 p[8];
#pragma unroll
                for (int u = 0; u < 8; ++u) p[u] = cv[k + u];
                f32x4 hv[8];
#pragma unroll
                for (int u = 0; u < 8; ++u) hv[u] = hl[(size_t)p[u].x * 32];
#pragma unroll
                for (int u = 0; u < 8; ++u) acc += __int_as_float(p[u].y) * hv[u];
            }
            for (; k < e; ++k) {
                i32x2 p = cv[k];
                acc += __int_as_float(p.y) * hl[(size_t)p.x * 32];
            }
        }
        rowdata[i] = acc;
    }

    // ---- phase 2: GEMM epilogue. lane computes out cols c0..c0+3 for its half's 4 rows ----
    const int c0 = l * 4;
    const int sbase = half << 5;                 // shfl source base for my half
    f32x4 oacc[4];
#pragma unroll
    for (int i = 0; i < 4; ++i) oacc[i] = (f32x4)(0.f);

    for (int k4 = 0; k4 < D / 4; ++k4) {         // k = 4*k4 + kk
        const int srcl = sbase + k4;
#pragma unroll
        for (int kk = 0; kk < 4; ++kk) {
            const f32x4 w = *(const f32x4*)&W[(k4 * 4 + kk) * D + c0];
#pragma unroll
            for (int i = 0; i < 4; ++i) {
                float hk = __shfl(rowdata[i][kk], srcl);
                oacc[i] += hk * w;
            }
        }
    }

    if (!CLASSIFY) {
#pragma unroll
        for (int i = 0; i < 4; ++i) {
            const int r = row0 + 2 * i + half;
            if (r < n) {
                f32x4 v;
                v.x = fmaxf(oacc[i].x, 0.f); v.y = fmaxf(oacc[i].y, 0.f);
                v.z = fmaxf(oacc[i].z, 0.f); v.w = fmaxf(oacc[i].w, 0.f);
                *(f32x4*)&O[(size_t)r * D + c0] = v;
            }
        }
    } else {
        // relu in registers
#pragma unroll
        for (int i = 0; i < 4; ++i) {
            oacc[i].x = fmaxf(oacc[i].x, 0.f); oacc[i].y = fmaxf(oacc[i].y, 0.f);
            oacc[i].z = fmaxf(oacc[i].z, 0.f); oacc[i].w = fmaxf(oacc[i].w, 0.f);
        }
        // ---- phase 3: classify. lane l: class j = l&15, k-range half kh = l>>4 ----
        const int j = l & 15;
        const int kh = l >> 4;                    // k in [64*kh, 64*kh+64)
        float lg[4] = {0.f, 0.f, 0.f, 0.f};
        for (int m4 = 0; m4 < 16; ++m4) {         // k = 64*kh + 4*m4 + kk
            const int srcl = sbase + kh * 16 + m4;
#pragma unroll
            for (int kk = 0; kk < 4; ++kk) {
                const int k = kh * 64 + m4 * 4 + kk;
                const float c = Cls[k * 16 + j];
#pragma unroll
                for (int i = 0; i < 4; ++i) {
                    float hk = __shfl(oacc[i][kk], srcl);
                    lg[i] += hk * c;
                }
            }
        }
        // combine k-halves: partner lane l^16 holds the other half of the sum
#pragma unroll
        for (int i = 0; i < 4; ++i) lg[i] += __shfl_xor(lg[i], 16);
        if (kh == 0) {                            // lanes with l<16 write class j
#pragma unroll
            for (int i = 0; i < 4; ++i) {
                const int r = row0 + 2 * i + half;
                if (r < n) O[(size_t)r * 16 + j] = lg[i] > 0.f ? 1.f : 0.f;
            }
        }
    }
}

extern "C" void kernel_launch(void* const* d_in, const int* in_sizes, int n_in,
                              void* d_out, int out_size, void* d_ws, size_t ws_size,
                              hipStream_t stream) {
    const float* x    = (const float*)d_in[0];
    const int*   erow = (const int*)d_in[1];
    const int*   ecol = (const int*)d_in[2];
    const float* ev   = (const float*)d_in[3];
    const float* w1   = (const float*)d_in[4];
    const float* w2   = (const float*)d_in[5];
    const float* cls  = (const float*)d_in[6];

    const int n  = in_sizes[0] / D;   // 100000
    const int nE = in_sizes[1];       // 1600000

    // workspace layout
    char*  ws     = (char*)d_ws;
    float* h      = (float*)ws;                 ws += (size_t)n * D * 4;   // 51.2 MB
    int*   deg    = (int*)ws;                   ws += (size_t)n * 4;
    int*   rowptr = (int*)ws;                   ws += (size_t)(n + 1) * 4;
    int*   rank   = (int*)ws;                   ws += (size_t)nE * 4;
    i32x2* cv     = (i32x2*)ws;                 ws += (size_t)nE * 8;      // packed col+val
    int*   bsums  = (int*)ws;                   ws += 256 * 4;

    const int nb = (n + 1023) / 1024;   // 98 <= 256

    dim3 blk(256);
    dim3 egrid((nE + 255) / 256);
    dim3 ngrid((n + 255) / 256);
    dim3 wgrid((n + 3) / 4);          // sortrow: 1 wave per row
    dim3 sgrid((n + 31) / 32);        // spmm_gemm: 32 rows per block (8 per wave)

    // ---- CSR build (deterministic final order by (col,valbits)) ----
    (void)hipMemsetAsync(deg, 0, (size_t)n * 4, stream);
    hist_rank_kernel<<<egrid, blk, 0, stream>>>(erow, deg, rank, nE);
    scan1_kernel<<<nb, blk, 0, stream>>>(deg, rowptr, bsums, n);
    scan2_kernel<<<1, blk, 0, stream>>>(bsums, nb);
    scan3_kernel<<<ngrid, blk, 0, stream>>>(rowptr, bsums, n);
    place_kernel<<<egrid, blk, 0, stream>>>(erow, rank, ecol, ev, rowptr, cv, nE);
    sortrow_wave_kernel<<<wgrid, blk, 0, stream>>>(rowptr, cv, n);

    // ---- layer 1: h = relu(spmm(x) @ w1) ----
    spmm_gemm_kernel<false><<<sgrid, blk, 0, stream>>>(x, rowptr, cv, w1, nullptr, h, n);

    // ---- layer 2 + classifier: out = (relu(spmm(h) @ w2) @ cls > 0) ----
    spmm_gemm_kernel<true><<<sgrid, blk, 0, stream>>>(h, rowptr, cv, w2, cls,
                                                      (float*)d_out, n);
}

// Round 13
// 473.031 us; speedup vs baseline: 1.1076x; 1.0029x over previous
//
#include <hip/hip_runtime.h>
#include <climits>

#define D 128

typedef float f32x4 __attribute__((ext_vector_type(4)));
typedef int   i32x2 __attribute__((ext_vector_type(2)));

// ---- CSR step 1: histogram + per-edge arrival rank (rank call-varying; sort canonicalizes) ----
__global__ __launch_bounds__(256) void hist_rank_kernel(const int* __restrict__ erow,
                                                        int* __restrict__ deg,
                                                        int* __restrict__ rank, int nE) {
    int e = blockIdx.x * 256 + threadIdx.x;
    if (e < nE) rank[e] = atomicAdd(&deg[erow[e]], 1);
}

// ---- scan phase 1: per-block scan of PADDED degrees (roundup8) ----
__global__ __launch_bounds__(256) void scan1_kernel(const int* __restrict__ deg,
                                                    int* __restrict__ rowptr,
                                                    int* __restrict__ blocksums, int n) {
    __shared__ int sd[256];
    const int t = threadIdx.x;
    const int idx = blockIdx.x * 1024 + t * 4;
    int4 v = make_int4(0, 0, 0, 0);
    if (idx + 3 < n) v = *(const int4*)&deg[idx];
    else {
        if (idx + 0 < n) v.x = deg[idx + 0];
        if (idx + 1 < n) v.y = deg[idx + 1];
        if (idx + 2 < n) v.z = deg[idx + 2];
        if (idx + 3 < n) v.w = deg[idx + 3];
    }
    v.x = (v.x + 7) & ~7; v.y = (v.y + 7) & ~7;   // pad rows to multiple of 8
    v.z = (v.z + 7) & ~7; v.w = (v.w + 7) & ~7;
    const int s = v.x + v.y + v.z + v.w;
    sd[t] = s;
    __syncthreads();
    for (int off = 1; off < 256; off <<= 1) {
        int tv = (t >= off) ? sd[t - off] : 0;
        __syncthreads();
        sd[t] += tv;
        __syncthreads();
    }
    const int excl = sd[t] - s;
    int a = excl + v.x, b = a + v.y, c = b + v.z, d = c + v.w;
    if (idx + 0 < n) rowptr[idx + 1] = a;
    if (idx + 1 < n) rowptr[idx + 2] = b;
    if (idx + 2 < n) rowptr[idx + 3] = c;
    if (idx + 3 < n) rowptr[idx + 4] = d;
    if (t == 255) blocksums[blockIdx.x] = sd[255];
}

// ---- scan phase 2: exclusive scan of block sums (nb <= 256) ----
__global__ __launch_bounds__(256) void scan2_kernel(int* __restrict__ blocksums, int nb) {
    __shared__ int sd[256];
    const int t = threadIdx.x;
    const int v = (t < nb) ? blocksums[t] : 0;
    sd[t] = v;
    __syncthreads();
    for (int off = 1; off < 256; off <<= 1) {
        int tv = (t >= off) ? sd[t - off] : 0;
        __syncthreads();
        sd[t] += tv;
        __syncthreads();
    }
    if (t < nb) blocksums[t] = sd[t] - v;   // exclusive
}

// ---- scan phase 3: add block offsets; finalize rowptr ----
__global__ __launch_bounds__(256) void scan3_kernel(int* __restrict__ rowptr,
                                                    const int* __restrict__ blocksums, int n) {
    int i = blockIdx.x * 256 + threadIdx.x;
    if (i < n) rowptr[i + 1] += blocksums[i >> 10];
    if (i == 0) rowptr[0] = 0;
}

// ---- CSR placement: one packed 8B record {col, valbits} per edge; no atomics ----
__global__ __launch_bounds__(256) void place_kernel(const int* __restrict__ erow,
                                                    const int* __restrict__ rank,
                                                    const int* __restrict__ ecol,
                                                    const float* __restrict__ ev,
                                                    const int* __restrict__ rowptr,
                                                    i32x2* __restrict__ cv, int nE) {
    int e = blockIdx.x * 256 + threadIdx.x;
    if (e >= nE) return;
    int pos = rowptr[erow[e]] + rank[e];
    i32x2 rec;
    rec.x = ecol[e];
    rec.y = __float_as_int(ev[e]);
    cv[pos] = rec;
}

// ---- canonicalize + pad-fill: wave rank-sort by u64(col,valbits); zero pads to row end ----
__global__ __launch_bounds__(256) void sortrow_wave_kernel(const int* __restrict__ rowptr,
                                                           const int* __restrict__ deg,
                                                           i32x2* __restrict__ cv, int n) {
    int row = blockIdx.x * 4 + (threadIdx.x >> 6);
    if (row >= n) return;
    const int lane = threadIdx.x & 63;
    const int s = rowptr[row], pe = rowptr[row + 1];
    const int dg = deg[row];
    const int npad = pe - s - dg;
    i32x2 zero; zero.x = 0; zero.y = 0;
    if (dg <= 64) {
        unsigned long long key = ~0ull;
        i32x2 rec = zero;
        if (lane < dg) {
            rec = cv[s + lane];
            key = ((unsigned long long)(unsigned)rec.x << 32) | (unsigned)rec.y;
        }
        int rank = 0;
        for (int i = 0; i < dg; ++i) {
            unsigned long long ki = __shfl(key, i);
            rank += (ki < key || (ki == key && i < lane)) ? 1 : 0;
        }
        if (lane < dg) cv[s + rank] = rec;    // wave-lockstep: reads precede writes
        if (lane < npad) cv[s + dg + lane] = zero;
    } else if (lane == 0) {                   // deg>64: ~never (deg ~ Poisson(16))
        for (int i = s + 1; i < s + dg; ++i) {
            i32x2 r_ = cv[i];
            unsigned long long k_ = ((unsigned long long)(unsigned)r_.x << 32) | (unsigned)r_.y;
            int j = i - 1;
            while (j >= s) {
                i32x2 rj = cv[j];
                unsigned long long kj = ((unsigned long long)(unsigned)rj.x << 32) | (unsigned)rj.y;
                if (kj <= k_) break;
                cv[j + 1] = rj;
                --j;
            }
            cv[j + 1] = r_;
        }
        for (int i = s + dg; i < pe; ++i) cv[i] = zero;
    }
}

// ---- per-wave fused spmm+GEMM(+classify): 4 rows/wave, tail-free gather, no LDS ----
template <bool CLASSIFY>
__global__ __launch_bounds__(256) void spmm_gemm_kernel(
        const float* __restrict__ h, const int* __restrict__ rowptr,
        const i32x2* __restrict__ cv, const float* __restrict__ W,
        const float* __restrict__ Cls, float* __restrict__ O, int n) {
    const int wid = (blockIdx.x * 256 + threadIdx.x) >> 6;   // global wave id
    const int lane = threadIdx.x & 63;
    const int half = lane >> 5;          // 0: rows +0,+2 ; 1: rows +1,+3
    const int l = lane & 31;
    const int row0 = wid * 4;
    if (row0 >= n) return;

    // ---- phase 1: gather 2 rows per half into registers (tail-free: degpad % 8 == 0) ----
    const f32x4* hl = (const f32x4*)h + l;
    f32x4 rowdata[2];
#pragma unroll
    for (int i = 0; i < 2; ++i) {
        const int r = row0 + 2 * i + half;
        f32x4 acc = (f32x4)(0.f);
        if (r < n) {
            const int s = rowptr[r], e = rowptr[r + 1];
            for (int k = s; k < e; k += 8) {
                i32x2 p[8];
#pragma unroll
                for (int u = 0; u < 8; ++u) p[u] = cv[k + u];
                f32x4 hv[8];
#pragma unroll
                for (int u = 0; u < 8; ++u) hv[u] = hl[(size_t)p[u].x * 32];
#pragma unroll
                for (int u = 0; u < 8; ++u) acc += __int_as_float(p[u].y) * hv[u];
            }
        }
        rowdata[i] = acc;
    }

    // ---- phase 2: GEMM epilogue via shfl-broadcast; lane owns out cols c0..c0+3 ----
    const int c0 = l * 4;
    const int sbase = half << 5;
    f32x4 oacc[2];
#pragma unroll
    for (int i = 0; i < 2; ++i) oacc[i] = (f32x4)(0.f);

    for (int k4 = 0; k4 < D / 4; ++k4) {
        const int srcl = sbase + k4;
#pragma unroll
        for (int kk = 0; kk < 4; ++kk) {
            const f32x4 w = *(const f32x4*)&W[(k4 * 4 + kk) * D + c0];
#pragma unroll
            for (int i = 0; i < 2; ++i) {
                float hk = __shfl(rowdata[i][kk], srcl);
                oacc[i] += hk * w;
            }
        }
    }

    if (!CLASSIFY) {
#pragma unroll
        for (int i = 0; i < 2; ++i) {
            const int r = row0 + 2 * i + half;
            if (r < n) {
                f32x4 v;
                v.x = fmaxf(oacc[i].x, 0.f); v.y = fmaxf(oacc[i].y, 0.f);
                v.z = fmaxf(oacc[i].z, 0.f); v.w = fmaxf(oacc[i].w, 0.f);
                *(f32x4*)&O[(size_t)r * D + c0] = v;
            }
        }
    } else {
        // relu in registers
#pragma unroll
        for (int i = 0; i < 2; ++i) {
            oacc[i].x = fmaxf(oacc[i].x, 0.f); oacc[i].y = fmaxf(oacc[i].y, 0.f);
            oacc[i].z = fmaxf(oacc[i].z, 0.f); oacc[i].w = fmaxf(oacc[i].w, 0.f);
        }
        // ---- phase 3: classify. lane l: class j = l&15, k-half kh = l>>4 ----
        const int j = l & 15;
        const int kh = l >> 4;
        float lg[2] = {0.f, 0.f};
        for (int m4 = 0; m4 < 16; ++m4) {
            const int srcl = sbase + kh * 16 + m4;
#pragma unroll
            for (int kk = 0; kk < 4; ++kk) {
                const int k = kh * 64 + m4 * 4 + kk;
                const float c = Cls[k * 16 + j];
#pragma unroll
                for (int i = 0; i < 2; ++i) {
                    float hk = __shfl(oacc[i][kk], srcl);
                    lg[i] += hk * c;
                }
            }
        }
#pragma unroll
        for (int i = 0; i < 2; ++i) lg[i] += __shfl_xor(lg[i], 16);
        if (kh == 0) {
#pragma unroll
            for (int i = 0; i < 2; ++i) {
                const int r = row0 + 2 * i + half;
                if (r < n) O[(size_t)r * 16 + j] = lg[i] > 0.f ? 1.f : 0.f;
            }
        }
    }
}

extern "C" void kernel_launch(void* const* d_in, const int* in_sizes, int n_in,
                              void* d_out, int out_size, void* d_ws, size_t ws_size,
                              hipStream_t stream) {
    const float* x    = (const float*)d_in[0];
    const int*   erow = (const int*)d_in[1];
    const int*   ecol = (const int*)d_in[2];
    const float* ev   = (const float*)d_in[3];
    const float* w1   = (const float*)d_in[4];
    const float* w2   = (const float*)d_in[5];
    const float* cls  = (const float*)d_in[6];

    const int n  = in_sizes[0] / D;   // 100000
    const int nE = in_sizes[1];       // 1600000

    // workspace layout (cv sized nE + 8n for padding)
    char*  ws     = (char*)d_ws;
    float* h      = (float*)ws;                 ws += (size_t)n * D * 4;   // 51.2 MB
    int*   deg    = (int*)ws;                   ws += (size_t)n * 4;
    int*   rowptr = (int*)ws;                   ws += (size_t)(n + 1) * 4;
    int*   rank   = (int*)ws;                   ws += (size_t)nE * 4;
    i32x2* cv     = (i32x2*)ws;                 ws += ((size_t)nE + 8 * (size_t)n) * 8;
    int*   bsums  = (int*)ws;                   ws += 256 * 4;

    const int nb = (n + 1023) / 1024;   // 98 <= 256

    dim3 blk(256);
    dim3 egrid((nE + 255) / 256);
    dim3 ngrid((n + 255) / 256);
    dim3 wgrid((n + 3) / 4);          // sortrow: 1 wave per row
    dim3 sgrid((n + 15) / 16);        // spmm_gemm: 16 rows per block (4 per wave)

    // ---- CSR build (deterministic final order by (col,valbits); rows padded to 8) ----
    (void)hipMemsetAsync(deg, 0, (size_t)n * 4, stream);
    hist_rank_kernel<<<egrid, blk, 0, stream>>>(erow, deg, rank, nE);
    scan1_kernel<<<nb, blk, 0, stream>>>(deg, rowptr, bsums, n);
    scan2_kernel<<<1, blk, 0, stream>>>(bsums, nb);
    scan3_kernel<<<ngrid, blk, 0, stream>>>(rowptr, bsums, n);
    place_kernel<<<egrid, blk, 0, stream>>>(erow, rank, ecol, ev, rowptr, cv, nE);
    sortrow_wave_kernel<<<wgrid, blk, 0, stream>>>(rowptr, deg, cv, n);

    // ---- layer 1: h = relu(spmm(x) @ w1) ----
    spmm_gemm_kernel<false><<<sgrid, blk, 0, stream>>>(x, rowptr, cv, w1, nullptr, h, n);

    // ---- layer 2 + classifier: out = (relu(spmm(h) @ w2) @ cls > 0) ----
    spmm_gemm_kernel<true><<<sgrid, blk, 0, stream>>>(h, rowptr, cv, w2, cls,
                                                      (float*)d_out, n);
}

// Round 14
// 437.965 us; speedup vs baseline: 1.1963x; 1.0801x over previous
//
#include <hip/hip_runtime.h>
#include <climits>

#define D 128

typedef float f32x4 __attribute__((ext_vector_type(4)));
typedef int   i32x2 __attribute__((ext_vector_type(2)));

// ---- CSR step 1: histogram + per-edge arrival rank (rank call-varying; sort canonicalizes) ----
__global__ __launch_bounds__(256) void hist_rank_kernel(const int* __restrict__ erow,
                                                        int* __restrict__ deg,
                                                        int* __restrict__ rank, int nE) {
    int e = blockIdx.x * 256 + threadIdx.x;
    if (e < nE) rank[e] = atomicAdd(&deg[erow[e]], 1);
}

// ---- scan phase 1: per-block scan of PADDED degrees (roundup8) ----
__global__ __launch_bounds__(256) void scan1_kernel(const int* __restrict__ deg,
                                                    int* __restrict__ rowptr,
                                                    int* __restrict__ blocksums, int n) {
    __shared__ int sd[256];
    const int t = threadIdx.x;
    const int idx = blockIdx.x * 1024 + t * 4;
    int4 v = make_int4(0, 0, 0, 0);
    if (idx + 3 < n) v = *(const int4*)&deg[idx];
    else {
        if (idx + 0 < n) v.x = deg[idx + 0];
        if (idx + 1 < n) v.y = deg[idx + 1];
        if (idx + 2 < n) v.z = deg[idx + 2];
        if (idx + 3 < n) v.w = deg[idx + 3];
    }
    v.x = (v.x + 7) & ~7; v.y = (v.y + 7) & ~7;   // pad rows to multiple of 8
    v.z = (v.z + 7) & ~7; v.w = (v.w + 7) & ~7;
    const int s = v.x + v.y + v.z + v.w;
    sd[t] = s;
    __syncthreads();
    for (int off = 1; off < 256; off <<= 1) {
        int tv = (t >= off) ? sd[t - off] : 0;
        __syncthreads();
        sd[t] += tv;
        __syncthreads();
    }
    const int excl = sd[t] - s;
    int a = excl + v.x, b = a + v.y, c = b + v.z, d = c + v.w;
    if (idx + 0 < n) rowptr[idx + 1] = a;
    if (idx + 1 < n) rowptr[idx + 2] = b;
    if (idx + 2 < n) rowptr[idx + 3] = c;
    if (idx + 3 < n) rowptr[idx + 4] = d;
    if (t == 255) blocksums[blockIdx.x] = sd[255];
}

// ---- scan phase 2: exclusive scan of block sums (nb <= 256) ----
__global__ __launch_bounds__(256) void scan2_kernel(int* __restrict__ blocksums, int nb) {
    __shared__ int sd[256];
    const int t = threadIdx.x;
    const int v = (t < nb) ? blocksums[t] : 0;
    sd[t] = v;
    __syncthreads();
    for (int off = 1; off < 256; off <<= 1) {
        int tv = (t >= off) ? sd[t - off] : 0;
        __syncthreads();
        sd[t] += tv;
        __syncthreads();
    }
    if (t < nb) blocksums[t] = sd[t] - v;   // exclusive
}

// ---- scan phase 3: add block offsets; finalize rowptr ----
__global__ __launch_bounds__(256) void scan3_kernel(int* __restrict__ rowptr,
                                                    const int* __restrict__ blocksums, int n) {
    int i = blockIdx.x * 256 + threadIdx.x;
    if (i < n) rowptr[i + 1] += blocksums[i >> 10];
    if (i == 0) rowptr[0] = 0;
}

// ---- CSR placement: one packed 8B record {col, valbits} per edge; no atomics ----
__global__ __launch_bounds__(256) void place_kernel(const int* __restrict__ erow,
                                                    const int* __restrict__ rank,
                                                    const int* __restrict__ ecol,
                                                    const float* __restrict__ ev,
                                                    const int* __restrict__ rowptr,
                                                    i32x2* __restrict__ cv, int nE) {
    int e = blockIdx.x * 256 + threadIdx.x;
    if (e >= nE) return;
    int pos = rowptr[erow[e]] + rank[e];
    i32x2 rec;
    rec.x = ecol[e];
    rec.y = __float_as_int(ev[e]);
    cv[pos] = rec;
}

// ---- canonicalize + pad-fill: wave rank-sort by u64(col,valbits); zero pads to row end ----
__global__ __launch_bounds__(256) void sortrow_wave_kernel(const int* __restrict__ rowptr,
                                                           const int* __restrict__ deg,
                                                           i32x2* __restrict__ cv, int n) {
    int row = blockIdx.x * 4 + (threadIdx.x >> 6);
    if (row >= n) return;
    const int lane = threadIdx.x & 63;
    const int s = rowptr[row], pe = rowptr[row + 1];
    const int dg = deg[row];
    const int npad = pe - s - dg;
    i32x2 zero; zero.x = 0; zero.y = 0;
    if (dg <= 64) {
        unsigned long long key = ~0ull;
        i32x2 rec = zero;
        if (lane < dg) {
            rec = cv[s + lane];
            key = ((unsigned long long)(unsigned)rec.x << 32) | (unsigned)rec.y;
        }
        int rank = 0;
        for (int i = 0; i < dg; ++i) {
            unsigned long long ki = __shfl(key, i);
            rank += (ki < key || (ki == key && i < lane)) ? 1 : 0;
        }
        if (lane < dg) cv[s + rank] = rec;    // wave-lockstep: reads precede writes
        if (lane < npad) cv[s + dg + lane] = zero;
    } else if (lane == 0) {                   // deg>64: ~never (deg ~ Poisson(16))
        for (int i = s + 1; i < s + dg; ++i) {
            i32x2 r_ = cv[i];
            unsigned long long k_ = ((unsigned long long)(unsigned)r_.x << 32) | (unsigned)r_.y;
            int j = i - 1;
            while (j >= s) {
                i32x2 rj = cv[j];
                unsigned long long kj = ((unsigned long long)(unsigned)rj.x << 32) | (unsigned)rj.y;
                if (kj <= k_) break;
                cv[j + 1] = rj;
                --j;
            }
            cv[j + 1] = r_;
        }
        for (int i = s + dg; i < pe; ++i) cv[i] = zero;
    }
}

// ---- per-wave fused spmm+GEMM(+classify): 8 rows/wave, DUAL-STREAM gather, no LDS ----
// subwave s (32 lanes) owns rows row0+s*4 .. +3; gathers them as 2 concurrent streams.
template <bool CLASSIFY>
__global__ __launch_bounds__(256) void spmm_gemm_kernel(
        const float* __restrict__ h, const int* __restrict__ rowptr,
        const i32x2* __restrict__ cv, const float* __restrict__ W,
        const float* __restrict__ Cls, float* __restrict__ O, int n) {
    const int wid = (blockIdx.x * 256 + threadIdx.x) >> 6;   // global wave id
    const int lane = threadIdx.x & 63;
    const int sw = lane >> 5;            // subwave 0/1
    const int l = lane & 31;
    const int row0 = wid * 8;
    if (row0 >= n) return;
    const int rbase = row0 + sw * 4;

    const f32x4* hl = (const f32x4*)h + l;
    f32x4 rowdata[4];

    // ---- phase 1: gather 4 rows as 2 dual-stream pairs (rows padded: deg%8==0) ----
#pragma unroll
    for (int jp = 0; jp < 2; ++jp) {
        const int rA = rbase + jp * 2;
        const int rB = rA + 1;
        int kA = 0, eA = 0, kB = 0, eB = 0;
        if (rA < n) { kA = rowptr[rA]; eA = rowptr[rA + 1]; }
        if (rB < n) { kB = rowptr[rB]; eB = rowptr[rB + 1]; }
        f32x4 accA = (f32x4)(0.f), accB = (f32x4)(0.f);
        while (kA < eA || kB < eB) {
            i32x2 pA[8], pB[8];
            const bool doA = kA < eA, doB = kB < eB;
            if (doA) {
#pragma unroll
                for (int u = 0; u < 8; ++u) pA[u] = cv[kA + u];
            }
            if (doB) {
#pragma unroll
                for (int u = 0; u < 8; ++u) pB[u] = cv[kB + u];
            }
            if (doA) {
                f32x4 hv[8];
#pragma unroll
                for (int u = 0; u < 8; ++u) hv[u] = hl[(size_t)pA[u].x * 32];
#pragma unroll
                for (int u = 0; u < 8; ++u) accA += __int_as_float(pA[u].y) * hv[u];
                kA += 8;
            }
            if (doB) {
                f32x4 hv[8];
#pragma unroll
                for (int u = 0; u < 8; ++u) hv[u] = hl[(size_t)pB[u].x * 32];
#pragma unroll
                for (int u = 0; u < 8; ++u) accB += __int_as_float(pB[u].y) * hv[u];
                kB += 8;
            }
        }
        rowdata[jp * 2]     = accA;
        rowdata[jp * 2 + 1] = accB;
    }

    // ---- phase 2: GEMM epilogue via shfl-broadcast; lane owns out cols c0..c0+3 ----
    const int c0 = l * 4;
    const int sbase = sw << 5;
    f32x4 oacc[4];
#pragma unroll
    for (int i = 0; i < 4; ++i) oacc[i] = (f32x4)(0.f);

    for (int k4 = 0; k4 < D / 4; ++k4) {
        const int srcl = sbase + k4;
#pragma unroll
        for (int kk = 0; kk < 4; ++kk) {
            const f32x4 w = *(const f32x4*)&W[(k4 * 4 + kk) * D + c0];
#pragma unroll
            for (int i = 0; i < 4; ++i) {
                float hk = __shfl(rowdata[i][kk], srcl);
                oacc[i] += hk * w;
            }
        }
    }

    if (!CLASSIFY) {
#pragma unroll
        for (int i = 0; i < 4; ++i) {
            const int r = rbase + i;
            if (r < n) {
                f32x4 v;
                v.x = fmaxf(oacc[i].x, 0.f); v.y = fmaxf(oacc[i].y, 0.f);
                v.z = fmaxf(oacc[i].z, 0.f); v.w = fmaxf(oacc[i].w, 0.f);
                *(f32x4*)&O[(size_t)r * D + c0] = v;
            }
        }
    } else {
        // relu in registers
#pragma unroll
        for (int i = 0; i < 4; ++i) {
            oacc[i].x = fmaxf(oacc[i].x, 0.f); oacc[i].y = fmaxf(oacc[i].y, 0.f);
            oacc[i].z = fmaxf(oacc[i].z, 0.f); oacc[i].w = fmaxf(oacc[i].w, 0.f);
        }
        // ---- phase 3: classify. lane l: class j = l&15, k-half kh = l>>4 ----
        const int j = l & 15;
        const int kh = l >> 4;
        float lg[4] = {0.f, 0.f, 0.f, 0.f};
        for (int m4 = 0; m4 < 16; ++m4) {
            const int srcl = sbase + kh * 16 + m4;
#pragma unroll
            for (int kk = 0; kk < 4; ++kk) {
                const int k = kh * 64 + m4 * 4 + kk;
                const float c = Cls[k * 16 + j];
#pragma unroll
                for (int i = 0; i < 4; ++i) {
                    float hk = __shfl(oacc[i][kk], srcl);
                    lg[i] += hk * c;
                }
            }
        }
#pragma unroll
        for (int i = 0; i < 4; ++i) lg[i] += __shfl_xor(lg[i], 16);
        if (kh == 0) {
#pragma unroll
            for (int i = 0; i < 4; ++i) {
                const int r = rbase + i;
                if (r < n) O[(size_t)r * 16 + j] = lg[i] > 0.f ? 1.f : 0.f;
            }
        }
    }
}

extern "C" void kernel_launch(void* const* d_in, const int* in_sizes, int n_in,
                              void* d_out, int out_size, void* d_ws, size_t ws_size,
                              hipStream_t stream) {
    const float* x    = (const float*)d_in[0];
    const int*   erow = (const int*)d_in[1];
    const int*   ecol = (const int*)d_in[2];
    const float* ev   = (const float*)d_in[3];
    const float* w1   = (const float*)d_in[4];
    const float* w2   = (const float*)d_in[5];
    const float* cls  = (const float*)d_in[6];

    const int n  = in_sizes[0] / D;   // 100000
    const int nE = in_sizes[1];       // 1600000

    // workspace layout (cv sized nE + 8n for padding)
    char*  ws     = (char*)d_ws;
    float* h      = (float*)ws;                 ws += (size_t)n * D * 4;   // 51.2 MB
    int*   deg    = (int*)ws;                   ws += (size_t)n * 4;
    int*   rowptr = (int*)ws;                   ws += (size_t)(n + 1) * 4;
    int*   rank   = (int*)ws;                   ws += (size_t)nE * 4;
    i32x2* cv     = (i32x2*)ws;                 ws += ((size_t)nE + 8 * (size_t)n) * 8;
    int*   bsums  = (int*)ws;                   ws += 256 * 4;

    const int nb = (n + 1023) / 1024;   // 98 <= 256

    dim3 blk(256);
    dim3 egrid((nE + 255) / 256);
    dim3 ngrid((n + 255) / 256);
    dim3 wgrid((n + 3) / 4);          // sortrow: 1 wave per row
    dim3 sgrid((n + 31) / 32);        // spmm_gemm: 32 rows per block (8 per wave)

    // ---- CSR build (deterministic final order by (col,valbits); rows padded to 8) ----
    (void)hipMemsetAsync(deg, 0, (size_t)n * 4, stream);
    hist_rank_kernel<<<egrid, blk, 0, stream>>>(erow, deg, rank, nE);
    scan1_kernel<<<nb, blk, 0, stream>>>(deg, rowptr, bsums, n);
    scan2_kernel<<<1, blk, 0, stream>>>(bsums, nb);
    scan3_kernel<<<ngrid, blk, 0, stream>>>(rowptr, bsums, n);
    place_kernel<<<egrid, blk, 0, stream>>>(erow, rank, ecol, ev, rowptr, cv, nE);
    sortrow_wave_kernel<<<wgrid, blk, 0, stream>>>(rowptr, deg, cv, n);

    // ---- layer 1: h = relu(spmm(x) @ w1) ----
    spmm_gemm_kernel<false><<<sgrid, blk, 0, stream>>>(x, rowptr, cv, w1, nullptr, h, n);

    // ---- layer 2 + classifier: out = (relu(spmm(h) @ w2) @ cls > 0) ----
    spmm_gemm_kernel<true><<<sgrid, blk, 0, stream>>>(h, rowptr, cv, w2, cls,
                                                      (float*)d_out, n);
}